// Round 9
// baseline (141.850 us; speedup 1.0000x reference)
//
#include <hip/hip_runtime.h>

// Problem constants
#define NROWS 16384   // 8*2048 tokens
#define DM    1024    // d_model
#define CD    64      // code depth
#define NC    2048    // num codes
#define KC    2047    // codes excluding index 0
#define NB    8       // batch
#define DECAY 0.99f

#define K3_BLOCKS 512

// d_out layout (floats, concatenated in reference return order)
#define OUT_HARD   0
#define OUT_IDX    1048576
#define OUT_COMMIT 1064960
#define OUT_EMB    1064961
#define OUT_CB     1064962
#define OUT_CS     1196034
#define OUT_CSUM   1198082

// d_ws layout (float offsets)
#define WS_Z      0                          // 1048576 f
#define WS_CN2    1048576                    // 2048 f ([2047]=+INF pad)
#define WS_BINC   1050624                    // 2048 u32
#define WS_SUMS   1052672                    // 131072 f
#define WS_CDIST  1183744                    // 8*2047 u32
#define WS_COMMIT 1200120                    // 512 f per-block partials
#define WS_ZN2    1200632                    // 16384 f
#define WS_N      1217016                    // 1 f (+3 pad)
#define WS_PART   1298940                    // 4*16384*64 f split-K partials (k1 only)
// k2 scratch ALIASES the PART region (k1 partials are dead by k2-launch):
#define WS_BV     WS_PART                    // 4*16384 f  per-group best value
#define WS_BI     (WS_PART + 65536)          // 4*16384 i32 per-group best idx (+1)
#define WS_IDXM   (WS_PART + 131072)         // 16384 i32 merged idx

#define F32_INF_BITS 0x7F800000u

// ---------------------------------------------------------------- K0: init
__global__ __launch_bounds__(256) void k0_init(const float* __restrict__ cb,
                                               float* __restrict__ ws) {
  int i = blockIdx.x * 256 + threadIdx.x;
  if (i < NC * CD) (ws + WS_SUMS)[i] = 0.0f;
  if (i < NC) {
    ((unsigned*)(ws + WS_BINC))[i] = 0u;
    float cn2;
    if (i < KC) {
      const float* c = cb + (size_t)(i + 1) * CD;
      float s0 = 0.f, s1 = 0.f;
      #pragma unroll
      for (int d = 0; d < CD; d += 2) { s0 = fmaf(c[d], c[d], s0); s1 = fmaf(c[d+1], c[d+1], s1); }
      cn2 = s0 + s1;
    } else {
      cn2 = __uint_as_float(F32_INF_BITS);
    }
    (ws + WS_CN2)[i] = cn2;
  }
  if (i < NB * KC) ((unsigned*)(ws + WS_CDIST))[i] = F32_INF_BITS;
}

// ------------- K1 (split-K): partial[kslice] = x[:,ks*256:+256] @ W^T slice
// grid 512 = 128 rowtiles x 4 kslices; 128 threads; 128x64 tile, 8x8/thread.
__global__ __launch_bounds__(128) void k1_split(const float* __restrict__ x,
                                                const float* __restrict__ W,
                                                float* __restrict__ ws) {
  __shared__ float xs[32][132];   // [k][row'] swizzled
  __shared__ float wls[32][68];   // [k][col]
  const int t = threadIdx.x;             // 0..127
  const int ks = blockIdx.x & 3;
  const int row0 = (blockIdx.x >> 2) * 128;
  const int kbase = ks * 256;
  const int tx = t & 7, ty = t >> 3;     // tx: 8 col-groups, ty: 16 row-groups
  const int sseg = t & 7, srow = t >> 3; // staging: seg 0..7, row-base 0..15

  float4 px[8], pw[4];
  auto ld = [&](int kt) {
    const int kk = kbase + kt * 32;
    #pragma unroll
    for (int it = 0; it < 8; ++it)
      px[it] = *(const float4*)(x + (size_t)(row0 + srow + 16 * it) * DM + kk + sseg * 4);
    #pragma unroll
    for (int it = 0; it < 4; ++it)
      pw[it] = *(const float4*)(W + (size_t)(srow + 16 * it) * DM + kk + sseg * 4);
  };
  ld(0);

  float acc[8][8];
  #pragma unroll
  for (int i = 0; i < 8; i++)
    #pragma unroll
    for (int j = 0; j < 8; j++) acc[i][j] = 0.f;

  for (int kt = 0; kt < 8; ++kt) {
    __syncthreads();
    const int sg4 = sseg * 4;
    #pragma unroll
    for (int it = 0; it < 8; ++it) {
      const int cpos = (srow + 16 * it) ^ ((sseg & 3) << 3);   // matches read swz ((d>>2)&3)
      xs[sg4 + 0][cpos] = px[it].x; xs[sg4 + 1][cpos] = px[it].y;
      xs[sg4 + 2][cpos] = px[it].z; xs[sg4 + 3][cpos] = px[it].w;
    }
    #pragma unroll
    for (int it = 0; it < 4; ++it) {
      const int wcol = srow + 16 * it;
      wls[sg4 + 0][wcol] = pw[it].x; wls[sg4 + 1][wcol] = pw[it].y;
      wls[sg4 + 2][wcol] = pw[it].z; wls[sg4 + 3][wcol] = pw[it].w;
    }
    __syncthreads();
    if (kt < 7) ld(kt + 1);

    #pragma unroll 4
    for (int dl = 0; dl < 32; ++dl) {
      const int xcol = (ty * 8) ^ (((dl >> 2) & 3) << 3);
      float4 xv0 = *(const float4*)(&xs[dl][xcol]);
      float4 xv1 = *(const float4*)(&xs[dl][xcol + 4]);
      float4 wv0 = *(const float4*)(&wls[dl][tx * 8]);
      float4 wv1 = *(const float4*)(&wls[dl][tx * 8 + 4]);
      float xz[8] = {xv0.x, xv0.y, xv0.z, xv0.w, xv1.x, xv1.y, xv1.z, xv1.w};
      float wc[8] = {wv0.x, wv0.y, wv0.z, wv0.w, wv1.x, wv1.y, wv1.z, wv1.w};
      #pragma unroll
      for (int i = 0; i < 8; i++)
        #pragma unroll
        for (int j = 0; j < 8; j++)
          acc[i][j] = fmaf(xz[i], wc[j], acc[i][j]);
    }
  }

  float* part = ws + WS_PART + (size_t)ks * NROWS * CD;
  #pragma unroll
  for (int i = 0; i < 8; i++) {
    const int row = row0 + ty * 8 + i;
    float4 v0, v1;
    v0.x = acc[i][0]; v0.y = acc[i][1]; v0.z = acc[i][2]; v0.w = acc[i][3];
    v1.x = acc[i][4]; v1.y = acc[i][5]; v1.z = acc[i][6]; v1.w = acc[i][7];
    *(float4*)(part + (size_t)row * CD + tx * 8) = v0;
    *(float4*)(part + (size_t)row * CD + tx * 8 + 4) = v1;
  }
}

// ------------- K1r: sum 4 partials + bias, row-normalize, write z/zn2
__global__ __launch_bounds__(256) void k1_reduce(const float* __restrict__ bdown,
                                                 float* __restrict__ ws) {
  const int t = threadIdx.x;
  const int tx = t & 15, ty = t >> 4;
  const int row = blockIdx.x * 16 + ty;
  const float* part = ws + WS_PART;
  const size_t off = (size_t)row * CD + tx * 4;

  float4 v0 = *(const float4*)(part + off);
  float4 v1 = *(const float4*)(part + (size_t)1 * NROWS * CD + off);
  float4 v2 = *(const float4*)(part + (size_t)2 * NROWS * CD + off);
  float4 v3 = *(const float4*)(part + (size_t)3 * NROWS * CD + off);
  float4 b  = *(const float4*)(bdown + tx * 4);
  float4 v;
  v.x = (v0.x + v1.x) + (v2.x + v3.x) + b.x;
  v.y = (v0.y + v1.y) + (v2.y + v3.y) + b.y;
  v.z = (v0.z + v1.z) + (v2.z + v3.z) + b.z;
  v.w = (v0.w + v1.w) + (v2.w + v3.w) + b.w;

  float ss = v.x * v.x + v.y * v.y + v.z * v.z + v.w * v.w;
  #pragma unroll
  for (int m = 1; m < 16; m <<= 1) ss += __shfl_xor(ss, m, 64);
  float inv = 1.0f / sqrtf(ss);   // uniform per-row scale: argmin-safe
  float4 zv; zv.x = v.x * inv; zv.y = v.y * inv; zv.z = v.z * inv; zv.w = v.w * inv;
  *(float4*)(ws + WS_Z + off) = zv;
  if (tx == 0) (ws + WS_ZN2)[row] = ss * inv * inv;
}

// ------------- K1 legacy (used only if ws too small for split-K partials)
__global__ __launch_bounds__(256) void k1_down(const float* __restrict__ x,
                                               const float* __restrict__ W,
                                               const float* __restrict__ bdown,
                                               float* __restrict__ ws) {
  __shared__ float xs[64][68];
  __shared__ float wls[64][68];
  const int t = threadIdx.x;
  const int row0 = blockIdx.x * 64;
  const int tx = t & 15, ty = t >> 4;

  int pr[4], pseg[4];
  #pragma unroll
  for (int it = 0; it < 4; ++it) { int c = t + it * 256; pr[it] = c >> 4; pseg[it] = c & 15; }

  float4 px[4], pw[4];
  #pragma unroll
  for (int it = 0; it < 4; ++it) {
    px[it] = *(const float4*)(x + (size_t)(row0 + pr[it]) * DM + pseg[it] * 4);
    pw[it] = *(const float4*)(W + (size_t)pr[it] * DM + pseg[it] * 4);
  }

  float acc[4][4];
  #pragma unroll
  for (int i = 0; i < 4; i++)
    #pragma unroll
    for (int j = 0; j < 4; j++) acc[i][j] = 0.f;

  for (int kt = 0; kt < 16; ++kt) {
    __syncthreads();
    #pragma unroll
    for (int it = 0; it < 4; ++it) {
      *(float4*)(&xs[pr[it]][pseg[it] * 4]) = px[it];
      *(float4*)(&wls[pr[it]][pseg[it] * 4]) = pw[it];
    }
    __syncthreads();
    if (kt < 15) {
      const int k0 = (kt + 1) * 64;
      #pragma unroll
      for (int it = 0; it < 4; ++it) {
        px[it] = *(const float4*)(x + (size_t)(row0 + pr[it]) * DM + k0 + pseg[it] * 4);
        pw[it] = *(const float4*)(W + (size_t)pr[it] * DM + k0 + pseg[it] * 4);
      }
    }
    #pragma unroll 4
    for (int k = 0; k < 64; k += 4) {
      float4 xv[4], wv[4];
      #pragma unroll
      for (int i = 0; i < 4; i++) xv[i] = *(const float4*)(&xs[ty * 4 + i][k]);
      #pragma unroll
      for (int j = 0; j < 4; j++) wv[j] = *(const float4*)(&wls[tx * 4 + j][k]);
      #pragma unroll
      for (int i = 0; i < 4; i++)
        #pragma unroll
        for (int j = 0; j < 4; j++)
          acc[i][j] = fmaf(xv[i].x, wv[j].x, fmaf(xv[i].y, wv[j].y,
                      fmaf(xv[i].z, wv[j].z, fmaf(xv[i].w, wv[j].w, acc[i][j]))));
    }
  }

  #pragma unroll
  for (int j = 0; j < 4; j++) {
    float bj = bdown[tx * 4 + j];
    #pragma unroll
    for (int i = 0; i < 4; i++) acc[i][j] += bj;
  }

  float* z = ws + WS_Z;
  float* zn2 = ws + WS_ZN2;
  #pragma unroll
  for (int i = 0; i < 4; i++) {
    float ss = acc[i][0] * acc[i][0] + acc[i][1] * acc[i][1] +
               acc[i][2] * acc[i][2] + acc[i][3] * acc[i][3];
    #pragma unroll
    for (int m = 1; m < 16; m <<= 1) ss += __shfl_xor(ss, m, 64);
    float inv = 1.0f / sqrtf(ss);
    float4 zv;
    zv.x = acc[i][0] * inv; zv.y = acc[i][1] * inv;
    zv.z = acc[i][2] * inv; zv.w = acc[i][3] * inv;
    int row = row0 + ty * 4 + i;
    *(float4*)(z + (size_t)row * CD + tx * 4) = zv;
    if (tx == 0) zn2[row] = ss * inv * inv;
  }
}

// ---- K2: distance GEMM + per-row argmin (per 512-code quarter) + column-min
// 8x8 thread tile (1.0 LDS B/MAC): block = 256 rows x 512 codes, 512 thr,
// grid 256 = 1 block/CU. z staged ONCE (66.5KB), 4 c-tiles of 128 codes
// (33.8KB), R3-proven 3-barrier schedule + reg prefetch. tx=t&15 gives
// 16 distinct c-read quads -> 2-way free with swizzle c^=((c>>5)&1)<<2;
// z reads are 4-address wave broadcasts. d=0..63 ascending fma chain ->
// bit-identical scores/argmin to R8.
__global__ __launch_bounds__(512) void k2_dist(const float* __restrict__ cbp,
                                               float* __restrict__ ws) {
  __shared__ float zT[64][260];   // [d][row 0..255]
  __shared__ float cT[64][132];   // [d][code']
  __shared__ float cn2s[128];
  __shared__ float zn2s[256];
  __shared__ unsigned colmin[128];

  const int t = threadIdx.x;
  const int gq = blockIdx.x & 3;           // code quarter: 512 codes
  const int rt = blockIdx.x >> 2;          // 0..63 rowtile
  const int row0 = rt << 8;                // 256 rows
  const int batch = rt >> 3;               // 8 rowtiles per batch
  const int tx = t & 15, ty = t >> 4;      // tx: 16 code-groups(x8), ty: 32 row-groups(x8)
  const float* z = ws + WS_Z;
  const float* cn2p = ws + WS_CN2;
  unsigned* cdist = (unsigned*)(ws + WS_CDIST) + (size_t)batch * KC;

  if (t < 256) zn2s[t] = (ws + WS_ZN2)[row0 + t];

  // stage zT once: 256 rows x 64 d; 2 threads/row, 8 segs (32 d) each.
  // write conflict: lane pairs differ by 4 d-rows -> bank +16 -> 2-way free.
  {
    const int sr = t >> 1, sodd = t & 1;
    float4 v[8];
    #pragma unroll
    for (int it = 0; it < 8; ++it)
      v[it] = *(const float4*)(z + (size_t)(row0 + sr) * CD + (sodd + 2 * it) * 4);
    #pragma unroll
    for (int it = 0; it < 8; ++it) {
      const int sg4 = (sodd + 2 * it) * 4;
      zT[sg4 + 0][sr] = v[it].x; zT[sg4 + 1][sr] = v[it].y;
      zT[sg4 + 2][sr] = v[it].z; zT[sg4 + 3][sr] = v[it].w;
    }
  }

  // c staging geometry: 128 codes/tile, 4 threads/code, 4 segs (16 d) each
  const int cr = t >> 2, cp = t & 3;
  const int ccol = cr ^ (((cr >> 5) & 1) << 2);   // swizzled cT column
  float4 pc[4];
  auto ldc = [&](int lt) {
    const int code = gq * 512 + lt * 128 + cr;    // 0-based in [0,2048)
    #pragma unroll
    for (int it = 0; it < 4; ++it)
      pc[it] = (code < KC) ? *(const float4*)(cbp + (size_t)(code + 1) * CD + (cp + 4 * it) * 4)
                           : make_float4(0.f, 0.f, 0.f, 0.f);
  };
  ldc(0);

  float bestv[8];
  int besti[8];
  #pragma unroll
  for (int i = 0; i < 8; i++) { bestv[i] = __uint_as_float(F32_INF_BITS); besti[i] = 0; }

  const int swz = ((tx >> 2) & 1) << 2;
  const int col0 = (tx * 8) ^ swz;        // 2-way free on read
  const int col1 = (tx * 8 + 4) ^ swz;
  const int ty8 = ty * 8;

  for (int lt = 0; lt < 4; ++lt) {
    __syncthreads();   // prev tile drained (and zT staged for lt=0)
    #pragma unroll
    for (int it = 0; it < 4; ++it) {
      const int sg4 = (cp + 4 * it) * 4;
      cT[sg4 + 0][ccol] = pc[it].x; cT[sg4 + 1][ccol] = pc[it].y;
      cT[sg4 + 2][ccol] = pc[it].z; cT[sg4 + 3][ccol] = pc[it].w;
    }
    if (t < 128) {
      cn2s[t] = cn2p[gq * 512 + lt * 128 + t];   // [2047] = +INF pad
      colmin[t] = F32_INF_BITS;
    }
    __syncthreads();
    if (lt < 3) ldc(lt + 1);       // prefetch next tile's codes into regs

    float acc[8][8];
    #pragma unroll
    for (int i = 0; i < 8; i++)
      #pragma unroll
      for (int j = 0; j < 8; j++) acc[i][j] = 0.f;

    #pragma unroll 8
    for (int d = 0; d < 64; ++d) {
      float4 za = *(const float4*)(&zT[d][ty8]);
      float4 zb = *(const float4*)(&zT[d][ty8 + 4]);
      float4 ca = *(const float4*)(&cT[d][col0]);
      float4 cb2 = *(const float4*)(&cT[d][col1]);
      float zz[8] = {za.x, za.y, za.z, za.w, zb.x, zb.y, zb.z, zb.w};
      float cc[8] = {ca.x, ca.y, ca.z, ca.w, cb2.x, cb2.y, cb2.z, cb2.w};
      #pragma unroll
      for (int i = 0; i < 8; i++)
        #pragma unroll
        for (int j = 0; j < 8; j++)
          acc[i][j] = fmaf(zz[i], cc[j], acc[i][j]);
    }

    // epilogue: score = cn2 - 2*dot (zn2 const per row: argmin-equivalent)
    const int jbase = gq * 512 + lt * 128;
    #pragma unroll
    for (int jl = 0; jl < 8; ++jl) {
      const int jloc = tx * 8 + jl;
      const int jg = jbase + jloc;
      const float c2 = cn2s[jloc];
      float colv = __uint_as_float(F32_INF_BITS);
      #pragma unroll
      for (int i = 0; i < 8; ++i) {
        float s = fmaf(-2.f, acc[i][jl], c2);
        if (s < bestv[i]) { bestv[i] = s; besti[i] = jg; }  // (lt,jl) ascending: first-index ties
        float v = zn2s[ty8 + i] + s;
        v = v < 0.f ? 0.f : v;          // clamp(d2,0): monotone under sqrt/min
        colv = v < colv ? v : colv;
      }
      // reduce colv across the 4 ty values in this wave (lanes ^16,^32 share tx)
      colv = fminf(colv, __shfl_xor(colv, 16, 64));
      colv = fminf(colv, __shfl_xor(colv, 32, 64));
      if ((t & 48) == 0) atomicMin(&colmin[jloc], __float_as_uint(colv));
    }
    __syncthreads();
    if (t < 128) {
      const int jg2 = jbase + t;
      if (jg2 < KC) atomicMin(&cdist[jg2], colmin[t]);
    }
  }

  // argmin reduce across the 16 tx lanes (masks 1..8 stay within ty-group)
  #pragma unroll
  for (int m = 1; m <= 8; m <<= 1) {
    #pragma unroll
    for (int i = 0; i < 8; i++) {
      float ov = __shfl_xor(bestv[i], m, 64);
      int oi = __shfl_xor(besti[i], m, 64);
      if (ov < bestv[i] || (ov == bestv[i] && oi < besti[i])) { bestv[i] = ov; besti[i] = oi; }
    }
  }
  if (tx == 0) {
    #pragma unroll
    for (int i = 0; i < 8; i++) {
      const int row = row0 + ty8 + i;
      (ws + WS_BV)[(size_t)gq * NROWS + row] = bestv[i];
      ((int*)(ws + WS_BI))[(size_t)gq * NROWS + row] = besti[i] + 1;
    }
  }
}

// ---- K2b: merge the 4 quarter-argmins (exact; quarters in ascending order)
__global__ __launch_bounds__(256) void k2b_merge(float* __restrict__ ws,
                                                 float* __restrict__ out) {
  const int row = blockIdx.x * 256 + threadIdx.x;
  float bv = (ws + WS_BV)[row];
  int bi = ((const int*)(ws + WS_BI))[row];
  #pragma unroll
  for (int g2 = 1; g2 < 4; ++g2) {
    float v = (ws + WS_BV)[(size_t)g2 * NROWS + row];
    int i2 = ((const int*)(ws + WS_BI))[(size_t)g2 * NROWS + row];
    if (v < bv) { bv = v; bi = i2; }        // tie -> lower quarter = first occurrence
  }
  ((int*)(ws + WS_IDXM))[row] = bi;
  out[OUT_IDX + row] = (float)bi;
}

// ------- K3: gather hard codes, commitment partials, scatter sums/bincounts
__global__ __launch_bounds__(256) void k3_scatter(const float* __restrict__ cb,
                                                  float* __restrict__ ws,
                                                  float* __restrict__ out) {
  const int t = threadIdx.x;
  const int lane = t & 63;
  const int w = t >> 6;
  const int rowbase = blockIdx.x * 32 + w * 8;
  const float* z = ws + WS_Z;
  const int* idxp = (const int*)(ws + WS_IDXM);

  int idx[8];
  #pragma unroll
  for (int r = 0; r < 8; ++r) idx[r] = idxp[rowbase + r];

  float sq = 0.f;
  #pragma unroll
  for (int r = 0; r < 8; ++r) {
    const int row = rowbase + r;
    const float c = cb[(size_t)idx[r] * CD + lane];
    const float zv = z[(size_t)row * CD + lane];
    out[OUT_HARD + (size_t)row * CD + lane] = zv + (c - zv);  // matches z + sg(hard - z)
    const float d = c - zv;
    sq = fmaf(d, d, sq);
    atomicAdd(ws + WS_SUMS + (size_t)idx[r] * CD + lane, zv);
    if (lane == 0) atomicAdd((unsigned*)(ws + WS_BINC) + idx[r], 1u);
  }

  __shared__ float red[4];
  #pragma unroll
  for (int m = 1; m < 64; m <<= 1) sq += __shfl_xor(sq, m, 64);
  if (lane == 0) red[w] = sq;
  __syncthreads();
  if (t == 0) (ws + WS_COMMIT)[blockIdx.x] = red[0] + red[1] + red[2] + red[3];
}

// --------- K4a: new_cs + n + losses (single block, small data only)
__global__ __launch_bounds__(1024) void k4a_stats(const float* __restrict__ cs_in,
                                                  float* __restrict__ ws,
                                                  float* __restrict__ out) {
  __shared__ float red[1024];
  const int t = threadIdx.x;
  const unsigned* binc = (const unsigned*)(ws + WS_BINC);

  float npart = 0.f;
  #pragma unroll
  for (int i = t; i < NC; i += 1024) {
    float nc = DECAY * cs_in[i] + (1.f - DECAY) * (float)binc[i];
    out[OUT_CS + i] = nc;
    npart += nc;
  }
  red[t] = npart; __syncthreads();
  for (int s = 512; s > 0; s >>= 1) { if (t < s) red[t] += red[t + s]; __syncthreads(); }
  if (t == 0) (ws + WS_N)[0] = red[0];
  __syncthreads();

  float cpart = 0.f;
  for (int j = t; j < K3_BLOCKS; j += 1024) cpart += (ws + WS_COMMIT)[j];
  red[t] = cpart; __syncthreads();
  for (int s = 512; s > 0; s >>= 1) { if (t < s) red[t] += red[t + s]; __syncthreads(); }
  float commit = red[0]; __syncthreads();

  const unsigned* cdist = (const unsigned*)(ws + WS_CDIST);
  float lsum = 0.f, ccount = 0.f;
  for (int j = t; j < KC; j += 1024) {
    if (binc[j + 1] == 0u) {
      ccount += 1.f;
      float srow = 0.f;
      #pragma unroll
      for (int b = 0; b < NB; b++) srow += sqrtf(__uint_as_float(cdist[b * KC + j]));
      lsum += srow;
    }
  }
  red[t] = lsum; __syncthreads();
  for (int s = 512; s > 0; s >>= 1) { if (t < s) red[t] += red[t + s]; __syncthreads(); }
  float totloss = red[0]; __syncthreads();
  red[t] = ccount; __syncthreads();
  for (int s = 512; s > 0; s >>= 1) { if (t < s) red[t] += red[t + s]; __syncthreads(); }
  float cnt = red[0] * (float)NB;
  if (t == 0) {
    out[OUT_COMMIT] = commit / (float)(NROWS * CD);
    out[OUT_EMB] = totloss / fmaxf(cnt, 1.f);
  }
}

// --------- K4b: new_csum, centroids, new_cb (512 blocks x 256)
__global__ __launch_bounds__(256) void k4b_update(const float* __restrict__ cb,
                                                  const float* __restrict__ csum_in,
                                                  const float* __restrict__ ws,
                                                  float* __restrict__ out) {
  const int e = blockIdx.x * 256 + threadIdx.x;   // 0 .. NC*CD-1
  const int k = e >> 6;
  const unsigned* binc = (const unsigned*)(ws + WS_BINC);
  const float n = (ws + WS_N)[0];
  const float denom = n + (float)NC * 1e-5f;

  float ncsum = DECAY * csum_in[e] + (1.f - DECAY) * (ws + WS_SUMS)[e];
  out[OUT_CSUM + e] = ncsum;
  float smoothed = (out[OUT_CS + k] + 1e-5f) * n / denom;
  float cent = ncsum / smoothed;
  float v = (binc[k] != 0u) ? cent : cb[e];
  if (k == 0) v = 0.f;
  out[OUT_CB + e] = v;
}

extern "C" void kernel_launch(void* const* d_in, const int* in_sizes, int n_in,
                              void* d_out, int out_size, void* d_ws, size_t ws_size,
                              hipStream_t stream) {
  const float* x    = (const float*)d_in[0];
  const float* W    = (const float*)d_in[1];
  const float* b    = (const float*)d_in[2];
  const float* cb   = (const float*)d_in[3];
  const float* cs   = (const float*)d_in[4];
  const float* csum = (const float*)d_in[5];
  float* out = (float*)d_out;
  float* ws  = (float*)d_ws;

  // split-K path needs partials: (WS_PART + 4*NROWS*CD) floats
  const size_t need = ((size_t)WS_PART + (size_t)4 * NROWS * CD) * sizeof(float);
  const bool use_split = ws_size >= need;   // host-side, deterministic

  hipLaunchKernelGGL(k0_init, dim3(512), dim3(256), 0, stream, cb, ws);
  if (use_split) {
    hipLaunchKernelGGL(k1_split,  dim3(512),  dim3(128), 0, stream, x, W, ws);
    hipLaunchKernelGGL(k1_reduce, dim3(1024), dim3(256), 0, stream, b, ws);
  } else {
    hipLaunchKernelGGL(k1_down, dim3(256), dim3(256), 0, stream, x, W, b, ws);
  }
  hipLaunchKernelGGL(k2_dist,   dim3(256),       dim3(512),  0, stream, cb, ws);
  hipLaunchKernelGGL(k2b_merge, dim3(64),        dim3(256),  0, stream, ws, out);
  hipLaunchKernelGGL(k3_scatter,dim3(K3_BLOCKS), dim3(256),  0, stream, cb, ws, out);
  hipLaunchKernelGGL(k4a_stats, dim3(1),         dim3(1024), 0, stream, cs, ws, out);
  hipLaunchKernelGGL(k4b_update,dim3(512),       dim3(256),  0, stream, cb, csum, ws, out);
}

// Round 10
// 138.680 us; speedup vs baseline: 1.0229x; 1.0229x over previous
//
#include <hip/hip_runtime.h>

// Problem constants
#define NROWS 16384   // 8*2048 tokens
#define DM    1024    // d_model
#define CD    64      // code depth
#define NC    2048    // num codes
#define KC    2047    // codes excluding index 0
#define NB    8       // batch
#define DECAY 0.99f

#define K3_BLOCKS 512

// d_out layout (floats, concatenated in reference return order)
#define OUT_HARD   0
#define OUT_IDX    1048576
#define OUT_COMMIT 1064960
#define OUT_EMB    1064961
#define OUT_CB     1064962
#define OUT_CS     1196034
#define OUT_CSUM   1198082

// d_ws layout (float offsets)
#define WS_Z      0                          // 1048576 f
#define WS_CN2    1048576                    // 2048 f ([2047]=+INF pad)
#define WS_BINC   1050624                    // 2048 u32
#define WS_SUMS   1052672                    // 131072 f
#define WS_CDIST  1183744                    // 8*2047 u32
#define WS_COMMIT 1200120                    // 512 f per-block partials
#define WS_ZN2    1200632                    // 16384 f
#define WS_N      1217016                    // 1 f (+3 pad)
#define WS_PART   1298940                    // 4*16384*64 f split-K partials (k1 only)
// k2 scratch ALIASES the PART region (k1 partials are dead by k2-launch):
#define WS_BV     WS_PART                    // 4*16384 f  per-quarter best value
#define WS_BI     (WS_PART + 65536)          // 4*16384 i32 per-quarter best idx (+1)

#define F32_INF_BITS 0x7F800000u

// ---------------------------------------------------------------- K0: init
__global__ __launch_bounds__(256) void k0_init(const float* __restrict__ cb,
                                               float* __restrict__ ws) {
  int i = blockIdx.x * 256 + threadIdx.x;
  if (i < NC * CD) (ws + WS_SUMS)[i] = 0.0f;
  if (i < NC) {
    ((unsigned*)(ws + WS_BINC))[i] = 0u;
    float cn2;
    if (i < KC) {
      const float* c = cb + (size_t)(i + 1) * CD;
      float s0 = 0.f, s1 = 0.f;
      #pragma unroll
      for (int d = 0; d < CD; d += 2) { s0 = fmaf(c[d], c[d], s0); s1 = fmaf(c[d+1], c[d+1], s1); }
      cn2 = s0 + s1;
    } else {
      cn2 = __uint_as_float(F32_INF_BITS);
    }
    (ws + WS_CN2)[i] = cn2;
  }
  if (i < NB * KC) ((unsigned*)(ws + WS_CDIST))[i] = F32_INF_BITS;
}

// ------------- K1 (split-K): partial[kslice] = x[:,ks*256:+256] @ W^T slice
// grid 512 = 128 rowtiles x 4 kslices; 128 threads; 128x64 tile, 8x8/thread.
__global__ __launch_bounds__(128) void k1_split(const float* __restrict__ x,
                                                const float* __restrict__ W,
                                                float* __restrict__ ws) {
  __shared__ float xs[32][132];   // [k][row'] swizzled
  __shared__ float wls[32][68];   // [k][col]
  const int t = threadIdx.x;             // 0..127
  const int ks = blockIdx.x & 3;
  const int row0 = (blockIdx.x >> 2) * 128;
  const int kbase = ks * 256;
  const int tx = t & 7, ty = t >> 3;     // tx: 8 col-groups, ty: 16 row-groups
  const int sseg = t & 7, srow = t >> 3; // staging: seg 0..7, row-base 0..15

  float4 px[8], pw[4];
  auto ld = [&](int kt) {
    const int kk = kbase + kt * 32;
    #pragma unroll
    for (int it = 0; it < 8; ++it)
      px[it] = *(const float4*)(x + (size_t)(row0 + srow + 16 * it) * DM + kk + sseg * 4);
    #pragma unroll
    for (int it = 0; it < 4; ++it)
      pw[it] = *(const float4*)(W + (size_t)(srow + 16 * it) * DM + kk + sseg * 4);
  };
  ld(0);

  float acc[8][8];
  #pragma unroll
  for (int i = 0; i < 8; i++)
    #pragma unroll
    for (int j = 0; j < 8; j++) acc[i][j] = 0.f;

  for (int kt = 0; kt < 8; ++kt) {
    __syncthreads();
    const int sg4 = sseg * 4;
    #pragma unroll
    for (int it = 0; it < 8; ++it) {
      const int cpos = (srow + 16 * it) ^ ((sseg & 3) << 3);   // matches read swz ((d>>2)&3)
      xs[sg4 + 0][cpos] = px[it].x; xs[sg4 + 1][cpos] = px[it].y;
      xs[sg4 + 2][cpos] = px[it].z; xs[sg4 + 3][cpos] = px[it].w;
    }
    #pragma unroll
    for (int it = 0; it < 4; ++it) {
      const int wcol = srow + 16 * it;
      wls[sg4 + 0][wcol] = pw[it].x; wls[sg4 + 1][wcol] = pw[it].y;
      wls[sg4 + 2][wcol] = pw[it].z; wls[sg4 + 3][wcol] = pw[it].w;
    }
    __syncthreads();
    if (kt < 7) ld(kt + 1);

    #pragma unroll 4
    for (int dl = 0; dl < 32; ++dl) {
      const int xcol = (ty * 8) ^ (((dl >> 2) & 3) << 3);
      float4 xv0 = *(const float4*)(&xs[dl][xcol]);
      float4 xv1 = *(const float4*)(&xs[dl][xcol + 4]);
      float4 wv0 = *(const float4*)(&wls[dl][tx * 8]);
      float4 wv1 = *(const float4*)(&wls[dl][tx * 8 + 4]);
      float xz[8] = {xv0.x, xv0.y, xv0.z, xv0.w, xv1.x, xv1.y, xv1.z, xv1.w};
      float wc[8] = {wv0.x, wv0.y, wv0.z, wv0.w, wv1.x, wv1.y, wv1.z, wv1.w};
      #pragma unroll
      for (int i = 0; i < 8; i++)
        #pragma unroll
        for (int j = 0; j < 8; j++)
          acc[i][j] = fmaf(xz[i], wc[j], acc[i][j]);
    }
  }

  float* part = ws + WS_PART + (size_t)ks * NROWS * CD;
  #pragma unroll
  for (int i = 0; i < 8; i++) {
    const int row = row0 + ty * 8 + i;
    float4 v0, v1;
    v0.x = acc[i][0]; v0.y = acc[i][1]; v0.z = acc[i][2]; v0.w = acc[i][3];
    v1.x = acc[i][4]; v1.y = acc[i][5]; v1.z = acc[i][6]; v1.w = acc[i][7];
    *(float4*)(part + (size_t)row * CD + tx * 8) = v0;
    *(float4*)(part + (size_t)row * CD + tx * 8 + 4) = v1;
  }
}

// ------------- K1r: sum 4 partials + bias, row-normalize, write z/zn2
__global__ __launch_bounds__(256) void k1_reduce(const float* __restrict__ bdown,
                                                 float* __restrict__ ws) {
  const int t = threadIdx.x;
  const int tx = t & 15, ty = t >> 4;
  const int row = blockIdx.x * 16 + ty;
  const float* part = ws + WS_PART;
  const size_t off = (size_t)row * CD + tx * 4;

  float4 v0 = *(const float4*)(part + off);
  float4 v1 = *(const float4*)(part + (size_t)1 * NROWS * CD + off);
  float4 v2 = *(const float4*)(part + (size_t)2 * NROWS * CD + off);
  float4 v3 = *(const float4*)(part + (size_t)3 * NROWS * CD + off);
  float4 b  = *(const float4*)(bdown + tx * 4);
  float4 v;
  v.x = (v0.x + v1.x) + (v2.x + v3.x) + b.x;
  v.y = (v0.y + v1.y) + (v2.y + v3.y) + b.y;
  v.z = (v0.z + v1.z) + (v2.z + v3.z) + b.z;
  v.w = (v0.w + v1.w) + (v2.w + v3.w) + b.w;

  float ss = v.x * v.x + v.y * v.y + v.z * v.z + v.w * v.w;
  #pragma unroll
  for (int m = 1; m < 16; m <<= 1) ss += __shfl_xor(ss, m, 64);
  float inv = 1.0f / sqrtf(ss);   // uniform per-row scale: argmin-safe
  float4 zv; zv.x = v.x * inv; zv.y = v.y * inv; zv.z = v.z * inv; zv.w = v.w * inv;
  *(float4*)(ws + WS_Z + off) = zv;
  if (tx == 0) (ws + WS_ZN2)[row] = ss * inv * inv;
}

// ------------- K1 legacy (used only if ws too small for split-K partials)
__global__ __launch_bounds__(256) void k1_down(const float* __restrict__ x,
                                               const float* __restrict__ W,
                                               const float* __restrict__ bdown,
                                               float* __restrict__ ws) {
  __shared__ float xs[64][68];
  __shared__ float wls[64][68];
  const int t = threadIdx.x;
  const int row0 = blockIdx.x * 64;
  const int tx = t & 15, ty = t >> 4;

  int pr[4], pseg[4];
  #pragma unroll
  for (int it = 0; it < 4; ++it) { int c = t + it * 256; pr[it] = c >> 4; pseg[it] = c & 15; }

  float4 px[4], pw[4];
  #pragma unroll
  for (int it = 0; it < 4; ++it) {
    px[it] = *(const float4*)(x + (size_t)(row0 + pr[it]) * DM + pseg[it] * 4);
    pw[it] = *(const float4*)(W + (size_t)pr[it] * DM + pseg[it] * 4);
  }

  float acc[4][4];
  #pragma unroll
  for (int i = 0; i < 4; i++)
    #pragma unroll
    for (int j = 0; j < 4; j++) acc[i][j] = 0.f;

  for (int kt = 0; kt < 16; ++kt) {
    __syncthreads();
    #pragma unroll
    for (int it = 0; it < 4; ++it) {
      *(float4*)(&xs[pr[it]][pseg[it] * 4]) = px[it];
      *(float4*)(&wls[pr[it]][pseg[it] * 4]) = pw[it];
    }
    __syncthreads();
    if (kt < 15) {
      const int k0 = (kt + 1) * 64;
      #pragma unroll
      for (int it = 0; it < 4; ++it) {
        px[it] = *(const float4*)(x + (size_t)(row0 + pr[it]) * DM + k0 + pseg[it] * 4);
        pw[it] = *(const float4*)(W + (size_t)pr[it] * DM + k0 + pseg[it] * 4);
      }
    }
    #pragma unroll 4
    for (int k = 0; k < 64; k += 4) {
      float4 xv[4], wv[4];
      #pragma unroll
      for (int i = 0; i < 4; i++) xv[i] = *(const float4*)(&xs[ty * 4 + i][k]);
      #pragma unroll
      for (int j = 0; j < 4; j++) wv[j] = *(const float4*)(&wls[tx * 4 + j][k]);
      #pragma unroll
      for (int i = 0; i < 4; i++)
        #pragma unroll
        for (int j = 0; j < 4; j++)
          acc[i][j] = fmaf(xv[i].x, wv[j].x, fmaf(xv[i].y, wv[j].y,
                      fmaf(xv[i].z, wv[j].z, fmaf(xv[i].w, wv[j].w, acc[i][j]))));
    }
  }

  #pragma unroll
  for (int j = 0; j < 4; j++) {
    float bj = bdown[tx * 4 + j];
    #pragma unroll
    for (int i = 0; i < 4; i++) acc[i][j] += bj;
  }

  float* z = ws + WS_Z;
  float* zn2 = ws + WS_ZN2;
  #pragma unroll
  for (int i = 0; i < 4; i++) {
    float ss = acc[i][0] * acc[i][0] + acc[i][1] * acc[i][1] +
               acc[i][2] * acc[i][2] + acc[i][3] * acc[i][3];
    #pragma unroll
    for (int m = 1; m < 16; m <<= 1) ss += __shfl_xor(ss, m, 64);
    float inv = 1.0f / sqrtf(ss);
    float4 zv;
    zv.x = acc[i][0] * inv; zv.y = acc[i][1] * inv;
    zv.z = acc[i][2] * inv; zv.w = acc[i][3] * inv;
    int row = row0 + ty * 4 + i;
    *(float4*)(z + (size_t)row * CD + tx * 4) = zv;
    if (tx == 0) zn2[row] = ss * inv * inv;
  }
}

// ---- K2: distance GEMM + per-row argmin (per 512-code quarter) + column-min
// EXACT R8 kernel (proven 70.7us, VALUBusy 60%, occ 38%): z resident full-d,
// per-tile c staging + reg prefetch, 3 barriers/tile, 8 rows x 4 codes,
// grid 512 = 2 blocks/CU (16 waves/CU — the empirically required residency).
__global__ __launch_bounds__(512) void k2_dist(const float* __restrict__ cbp,
                                               float* __restrict__ ws) {
  __shared__ float zT[64][132];   // [d][row 0..127]
  __shared__ float cT[64][132];   // [d][code']
  __shared__ float cn2s[128];
  __shared__ float zn2s[128];
  __shared__ unsigned colmin[128];

  const int t = threadIdx.x;
  const int gq = blockIdx.x & 3;           // code quarter: 512 codes
  const int rt = blockIdx.x >> 2;          // 0..127 rowtile
  const int row0 = rt << 7;                // 128 rows
  const int batch = rt >> 4;               // 16 rowtiles per batch
  const int tx = t & 31, ty = t >> 5;      // tx: 32 code-groups(x4), ty: 16 row-groups(x8)
  const float* z = ws + WS_Z;
  const float* cn2p = ws + WS_CN2;
  unsigned* cdist = (unsigned*)(ws + WS_CDIST) + (size_t)batch * KC;

  if (t < 128) zn2s[t] = (ws + WS_ZN2)[row0 + t];

  // stage zT once: 128 rows x 64 d; 4 threads/row, 4 segs (16 d) each
  {
    const int sr = t >> 2, sp = t & 3;
    float4 v[4];
    #pragma unroll
    for (int it = 0; it < 4; ++it)
      v[it] = *(const float4*)(z + (size_t)(row0 + sr) * CD + (sp + 4 * it) * 4);
    #pragma unroll
    for (int it = 0; it < 4; ++it) {
      const int sg4 = (sp + 4 * it) * 4;
      zT[sg4 + 0][sr] = v[it].x; zT[sg4 + 1][sr] = v[it].y;
      zT[sg4 + 2][sr] = v[it].z; zT[sg4 + 3][sr] = v[it].w;
    }
  }

  // c staging geometry: 128 codes/tile, 4 threads/code, 4 segs each
  const int cr = t >> 2, cp = t & 3;
  const int ccol = cr ^ (((cr >> 5) & 3) << 2);   // swizzled cT column
  float4 pc[4];
  auto ldc = [&](int lt) {
    const int code = gq * 512 + lt * 128 + cr;    // 0-based in [0,2048)
    #pragma unroll
    for (int it = 0; it < 4; ++it)
      pc[it] = (code < KC) ? *(const float4*)(cbp + (size_t)(code + 1) * CD + (cp + 4 * it) * 4)
                           : make_float4(0.f, 0.f, 0.f, 0.f);
  };
  ldc(0);

  float bestv[8];
  int besti[8];
  #pragma unroll
  for (int i = 0; i < 8; i++) { bestv[i] = __uint_as_float(F32_INF_BITS); besti[i] = 0; }

  const int ccol0 = (tx * 4) ^ (((tx >> 3) & 3) << 2);   // read col for 4 codes

  for (int lt = 0; lt < 4; ++lt) {
    __syncthreads();   // prev tile fully drained (and zT ready on first iter)
    #pragma unroll
    for (int it = 0; it < 4; ++it) {
      const int sg4 = (cp + 4 * it) * 4;
      cT[sg4 + 0][ccol] = pc[it].x; cT[sg4 + 1][ccol] = pc[it].y;
      cT[sg4 + 2][ccol] = pc[it].z; cT[sg4 + 3][ccol] = pc[it].w;
    }
    if (t < 128) {
      cn2s[t] = cn2p[gq * 512 + lt * 128 + t];   // [2047] = +INF pad
      colmin[t] = F32_INF_BITS;
    }
    __syncthreads();
    if (lt < 3) ldc(lt + 1);       // prefetch next tile's codes into regs

    float acc[8][4];
    #pragma unroll
    for (int i = 0; i < 8; i++)
      #pragma unroll
      for (int j = 0; j < 4; j++) acc[i][j] = 0.f;

    #pragma unroll 8
    for (int d = 0; d < 64; ++d) {
      float4 za = *(const float4*)(&zT[d][ty * 8]);
      float4 zb = *(const float4*)(&zT[d][ty * 8 + 4]);
      float4 cv = *(const float4*)(&cT[d][ccol0]);
      float zz[8] = {za.x, za.y, za.z, za.w, zb.x, zb.y, zb.z, zb.w};
      float cc[4] = {cv.x, cv.y, cv.z, cv.w};
      #pragma unroll
      for (int i = 0; i < 8; i++)
        #pragma unroll
        for (int j = 0; j < 4; j++)
          acc[i][j] = fmaf(zz[i], cc[j], acc[i][j]);
    }

    // epilogue: score = cn2 - 2*dot (zn2 const per row: argmin-equivalent)
    const int jbase = gq * 512 + lt * 128;
    #pragma unroll
    for (int jl = 0; jl < 4; ++jl) {
      const int jloc = tx * 4 + jl;
      const int jg = jbase + jloc;
      const float c2 = cn2s[jloc];
      float colv = __uint_as_float(F32_INF_BITS);
      #pragma unroll
      for (int i = 0; i < 8; ++i) {
        float s = fmaf(-2.f, acc[i][jl], c2);
        if (s < bestv[i]) { bestv[i] = s; besti[i] = jg; }  // (lt,jl) ascending: first-index ties
        float v = zn2s[ty * 8 + i] + s;
        v = v < 0.f ? 0.f : v;          // clamp(d2,0): monotone under sqrt/min
        colv = v < colv ? v : colv;
      }
      // reduce colv across the 2 ty values in this wave (lane ^32 shares tx)
      colv = fminf(colv, __shfl_xor(colv, 32, 64));
      if ((t & 32) == 0) atomicMin(&colmin[jloc], __float_as_uint(colv));
    }
    __syncthreads();
    if (t < 128) {
      const int jg2 = jbase + t;
      if (jg2 < KC) atomicMin(&cdist[jg2], colmin[t]);
    }
  }

  // argmin reduce across the 32 tx lanes (masks 1..16 stay within same ty)
  #pragma unroll
  for (int m = 1; m <= 16; m <<= 1) {
    #pragma unroll
    for (int i = 0; i < 8; i++) {
      float ov = __shfl_xor(bestv[i], m, 64);
      int oi = __shfl_xor(besti[i], m, 64);
      if (ov < bestv[i] || (ov == bestv[i] && oi < besti[i])) { bestv[i] = ov; besti[i] = oi; }
    }
  }
  if (tx == 0) {
    #pragma unroll
    for (int i = 0; i < 8; i++) {
      const int row = row0 + ty * 8 + i;
      (ws + WS_BV)[(size_t)gq * NROWS + row] = bestv[i];
      ((int*)(ws + WS_BI))[(size_t)gq * NROWS + row] = besti[i] + 1;
    }
  }
}

// ------- K3: inline quarter-argmin merge + gather hard codes + commitment
//         partials + scatter sums/bincounts (k2b fused in).
__global__ __launch_bounds__(256) void k3_scatter(const float* __restrict__ cb,
                                                  float* __restrict__ ws,
                                                  float* __restrict__ out) {
  const int t = threadIdx.x;
  const int lane = t & 63;
  const int w = t >> 6;
  const int rowbase = blockIdx.x * 32 + w * 8;
  const float* z = ws + WS_Z;

  // inline merge of the 4 quarter-argmins (ascending quarters, strict < ->
  // lowest quarter wins ties = first occurrence; identical to old k2b).
  const int myrow = rowbase + (lane & 7);
  float bv = (ws + WS_BV)[myrow];
  int myidx = ((const int*)(ws + WS_BI))[myrow];
  #pragma unroll
  for (int g2 = 1; g2 < 4; ++g2) {
    float v = (ws + WS_BV)[(size_t)g2 * NROWS + myrow];
    int i2 = ((const int*)(ws + WS_BI))[(size_t)g2 * NROWS + myrow];
    if (v < bv) { bv = v; myidx = i2; }
  }
  if (lane < 8) out[OUT_IDX + myrow] = (float)myidx;

  float sq = 0.f;
  #pragma unroll
  for (int r = 0; r < 8; ++r) {
    const int idx = __shfl(myidx, r, 8);   // idx for row rowbase+r (group-uniform)
    const int row = rowbase + r;
    const float c = cb[(size_t)idx * CD + lane];
    const float zv = z[(size_t)row * CD + lane];
    out[OUT_HARD + (size_t)row * CD + lane] = zv + (c - zv);  // matches z + sg(hard - z)
    const float d = c - zv;
    sq = fmaf(d, d, sq);
    atomicAdd(ws + WS_SUMS + (size_t)idx * CD + lane, zv);
    if (lane == 0) atomicAdd((unsigned*)(ws + WS_BINC) + idx, 1u);
  }

  __shared__ float red[4];
  #pragma unroll
  for (int m = 1; m < 64; m <<= 1) sq += __shfl_xor(sq, m, 64);
  if (lane == 0) red[w] = sq;
  __syncthreads();
  if (t == 0) (ws + WS_COMMIT)[blockIdx.x] = red[0] + red[1] + red[2] + red[3];
}

// --------- K4a: new_cs + n + losses (single block, small data only)
__global__ __launch_bounds__(1024) void k4a_stats(const float* __restrict__ cs_in,
                                                  float* __restrict__ ws,
                                                  float* __restrict__ out) {
  __shared__ float red[1024];
  const int t = threadIdx.x;
  const unsigned* binc = (const unsigned*)(ws + WS_BINC);

  float npart = 0.f;
  #pragma unroll
  for (int i = t; i < NC; i += 1024) {
    float nc = DECAY * cs_in[i] + (1.f - DECAY) * (float)binc[i];
    out[OUT_CS + i] = nc;
    npart += nc;
  }
  red[t] = npart; __syncthreads();
  for (int s = 512; s > 0; s >>= 1) { if (t < s) red[t] += red[t + s]; __syncthreads(); }
  if (t == 0) (ws + WS_N)[0] = red[0];
  __syncthreads();

  float cpart = 0.f;
  for (int j = t; j < K3_BLOCKS; j += 1024) cpart += (ws + WS_COMMIT)[j];
  red[t] = cpart; __syncthreads();
  for (int s = 512; s > 0; s >>= 1) { if (t < s) red[t] += red[t + s]; __syncthreads(); }
  float commit = red[0]; __syncthreads();

  const unsigned* cdist = (const unsigned*)(ws + WS_CDIST);
  float lsum = 0.f, ccount = 0.f;
  for (int j = t; j < KC; j += 1024) {
    if (binc[j + 1] == 0u) {
      ccount += 1.f;
      float srow = 0.f;
      #pragma unroll
      for (int b = 0; b < NB; b++) srow += sqrtf(__uint_as_float(cdist[b * KC + j]));
      lsum += srow;
    }
  }
  red[t] = lsum; __syncthreads();
  for (int s = 512; s > 0; s >>= 1) { if (t < s) red[t] += red[t + s]; __syncthreads(); }
  float totloss = red[0]; __syncthreads();
  red[t] = ccount; __syncthreads();
  for (int s = 512; s > 0; s >>= 1) { if (t < s) red[t] += red[t + s]; __syncthreads(); }
  float cnt = red[0] * (float)NB;
  if (t == 0) {
    out[OUT_COMMIT] = commit / (float)(NROWS * CD);
    out[OUT_EMB] = totloss / fmaxf(cnt, 1.f);
  }
}

// --------- K4b: new_csum, centroids, new_cb (512 blocks x 256)
__global__ __launch_bounds__(256) void k4b_update(const float* __restrict__ cb,
                                                  const float* __restrict__ csum_in,
                                                  const float* __restrict__ ws,
                                                  float* __restrict__ out) {
  const int e = blockIdx.x * 256 + threadIdx.x;   // 0 .. NC*CD-1
  const int k = e >> 6;
  const unsigned* binc = (const unsigned*)(ws + WS_BINC);
  const float n = (ws + WS_N)[0];
  const float denom = n + (float)NC * 1e-5f;

  float ncsum = DECAY * csum_in[e] + (1.f - DECAY) * (ws + WS_SUMS)[e];
  out[OUT_CSUM + e] = ncsum;
  float smoothed = (out[OUT_CS + k] + 1e-5f) * n / denom;
  float cent = ncsum / smoothed;
  float v = (binc[k] != 0u) ? cent : cb[e];
  if (k == 0) v = 0.f;
  out[OUT_CB + e] = v;
}

extern "C" void kernel_launch(void* const* d_in, const int* in_sizes, int n_in,
                              void* d_out, int out_size, void* d_ws, size_t ws_size,
                              hipStream_t stream) {
  const float* x    = (const float*)d_in[0];
  const float* W    = (const float*)d_in[1];
  const float* b    = (const float*)d_in[2];
  const float* cb   = (const float*)d_in[3];
  const float* cs   = (const float*)d_in[4];
  const float* csum = (const float*)d_in[5];
  float* out = (float*)d_out;
  float* ws  = (float*)d_ws;

  // split-K path needs partials: (WS_PART + 4*NROWS*CD) floats
  const size_t need = ((size_t)WS_PART + (size_t)4 * NROWS * CD) * sizeof(float);
  const bool use_split = ws_size >= need;   // host-side, deterministic

  hipLaunchKernelGGL(k0_init, dim3(512), dim3(256), 0, stream, cb, ws);
  if (use_split) {
    hipLaunchKernelGGL(k1_split,  dim3(512),  dim3(128), 0, stream, x, W, ws);
    hipLaunchKernelGGL(k1_reduce, dim3(1024), dim3(256), 0, stream, b, ws);
  } else {
    hipLaunchKernelGGL(k1_down, dim3(256), dim3(256), 0, stream, x, W, b, ws);
  }
  hipLaunchKernelGGL(k2_dist,   dim3(512),       dim3(512),  0, stream, cb, ws);
  hipLaunchKernelGGL(k3_scatter,dim3(K3_BLOCKS), dim3(256),  0, stream, cb, ws, out);
  hipLaunchKernelGGL(k4a_stats, dim3(1),         dim3(1024), 0, stream, cs, ws, out);
  hipLaunchKernelGGL(k4b_update,dim3(512),       dim3(256),  0, stream, cb, csum, ws, out);
}

// Round 11
// 133.223 us; speedup vs baseline: 1.0648x; 1.0410x over previous
//
#include <hip/hip_runtime.h>

// Problem constants
#define NROWS 16384   // 8*2048 tokens
#define DM    1024    // d_model
#define CD    64      // code depth
#define NC    2048    // num codes
#define KC    2047    // codes excluding index 0
#define NB    8       // batch
#define DECAY 0.99f

#define K3_BLOCKS 512

// d_out layout (floats, concatenated in reference return order)
#define OUT_HARD   0
#define OUT_IDX    1048576
#define OUT_COMMIT 1064960
#define OUT_EMB    1064961
#define OUT_CB     1064962
#define OUT_CS     1196034
#define OUT_CSUM   1198082

// d_ws layout (float offsets)
#define WS_Z      0                          // 1048576 f
#define WS_CN2    1048576                    // 2048 f ([2047]=+INF pad)
#define WS_BINC   1050624                    // 2048 u32
#define WS_SUMS   1052672                    // 131072 f
#define WS_CDIST  1183744                    // 8*2047 u32
#define WS_COMMIT 1200120                    // 512 f per-block partials
#define WS_ZN2    1200632                    // 16384 f
#define WS_N      1217016                    // 1 f (+3 pad)
#define WS_PART   1298940                    // 4*16384*64 f split-K partials (k1 only)
// k2 scratch ALIASES the PART region (k1 partials are dead by k2-launch):
#define WS_BV     WS_PART                    // 4*16384 f  per-quarter best value
#define WS_BI     (WS_PART + 65536)          // 4*16384 i32 per-quarter best idx (+1)

#define F32_INF_BITS 0x7F800000u

// ---------------------------------------------------------------- K0: init
__global__ __launch_bounds__(256) void k0_init(const float* __restrict__ cb,
                                               float* __restrict__ ws) {
  int i = blockIdx.x * 256 + threadIdx.x;
  if (i < NC * CD) (ws + WS_SUMS)[i] = 0.0f;
  if (i < NC) {
    ((unsigned*)(ws + WS_BINC))[i] = 0u;
    float cn2;
    if (i < KC) {
      const float* c = cb + (size_t)(i + 1) * CD;
      float s0 = 0.f, s1 = 0.f;
      #pragma unroll
      for (int d = 0; d < CD; d += 2) { s0 = fmaf(c[d], c[d], s0); s1 = fmaf(c[d+1], c[d+1], s1); }
      cn2 = s0 + s1;
    } else {
      cn2 = __uint_as_float(F32_INF_BITS);
    }
    (ws + WS_CN2)[i] = cn2;
  }
  if (i < NB * KC) ((unsigned*)(ws + WS_CDIST))[i] = F32_INF_BITS;
}

// ------------- K1 (split-K): partial[kslice] = x[:,ks*256:+256] @ W^T slice
// v2: 256 thr/block, 8 rows x 4 cols/thread (k2's proven read geometry),
// BK=64, grid 512 = 128 rowtiles x 4 kslices -> 2 blocks/CU x 4 waves =
// 8 waves/CU with cross-block barrier overlap (vs 4 waves/CU before).
// Each acc chain is d-ascending per (row,col,kslice) -> partials bit-identical
// to the previous passing kernel.
__global__ __launch_bounds__(256) void k1_split(const float* __restrict__ x,
                                                const float* __restrict__ W,
                                                float* __restrict__ ws) {
  __shared__ float xs[64][132];   // [k][row'] swizzled
  __shared__ float wls[64][68];   // [k][col]
  const int t = threadIdx.x;             // 0..255
  const int ks = blockIdx.x & 3;
  const int row0 = (blockIdx.x >> 2) * 128;
  const int kbase = ks * 256;
  const int tx = t & 15, ty = t >> 4;    // tx: 16 col-groups(x4), ty: 16 row-groups(x8)
  const int sseg = t & 15, srow = t >> 4; // staging: seg 0..15 (4k each), row-base 0..15

  float4 px[8], pw[4];
  auto ld = [&](int kt) {
    const int kk = kbase + kt * 64;
    #pragma unroll
    for (int it = 0; it < 8; ++it)
      px[it] = *(const float4*)(x + (size_t)(row0 + srow + 16 * it) * DM + kk + sseg * 4);
    #pragma unroll
    for (int it = 0; it < 4; ++it)
      pw[it] = *(const float4*)(W + (size_t)(srow + 16 * it) * DM + kk + sseg * 4);
  };
  ld(0);

  float acc[8][4];
  #pragma unroll
  for (int i = 0; i < 8; i++)
    #pragma unroll
    for (int j = 0; j < 4; j++) acc[i][j] = 0.f;

  for (int kt = 0; kt < 4; ++kt) {
    __syncthreads();
    const int sg4 = sseg * 4;
    #pragma unroll
    for (int it = 0; it < 8; ++it) {
      const int cpos = (srow + 16 * it) ^ ((sseg & 3) << 3);   // matches read swz ((dl>>2)&3)
      xs[sg4 + 0][cpos] = px[it].x; xs[sg4 + 1][cpos] = px[it].y;
      xs[sg4 + 2][cpos] = px[it].z; xs[sg4 + 3][cpos] = px[it].w;
    }
    #pragma unroll
    for (int it = 0; it < 4; ++it) {
      const int wcol = srow + 16 * it;
      wls[sg4 + 0][wcol] = pw[it].x; wls[sg4 + 1][wcol] = pw[it].y;
      wls[sg4 + 2][wcol] = pw[it].z; wls[sg4 + 3][wcol] = pw[it].w;
    }
    __syncthreads();
    if (kt < 3) ld(kt + 1);

    #pragma unroll 8
    for (int dl = 0; dl < 64; ++dl) {
      const int xcol = (ty * 8) ^ (((dl >> 2) & 3) << 3);
      float4 xv0 = *(const float4*)(&xs[dl][xcol]);
      float4 xv1 = *(const float4*)(&xs[dl][xcol + 4]);
      float4 wv  = *(const float4*)(&wls[dl][tx * 4]);
      float xz[8] = {xv0.x, xv0.y, xv0.z, xv0.w, xv1.x, xv1.y, xv1.z, xv1.w};
      float wc[4] = {wv.x, wv.y, wv.z, wv.w};
      #pragma unroll
      for (int i = 0; i < 8; i++)
        #pragma unroll
        for (int j = 0; j < 4; j++)
          acc[i][j] = fmaf(xz[i], wc[j], acc[i][j]);
    }
  }

  float* part = ws + WS_PART + (size_t)ks * NROWS * CD;
  #pragma unroll
  for (int i = 0; i < 8; i++) {
    const int row = row0 + ty * 8 + i;
    float4 v; v.x = acc[i][0]; v.y = acc[i][1]; v.z = acc[i][2]; v.w = acc[i][3];
    *(float4*)(part + (size_t)row * CD + tx * 4) = v;
  }
}

// ------------- K1r: sum 4 partials + bias, row-normalize, write z/zn2
__global__ __launch_bounds__(256) void k1_reduce(const float* __restrict__ bdown,
                                                 float* __restrict__ ws) {
  const int t = threadIdx.x;
  const int tx = t & 15, ty = t >> 4;
  const int row = blockIdx.x * 16 + ty;
  const float* part = ws + WS_PART;
  const size_t off = (size_t)row * CD + tx * 4;

  float4 v0 = *(const float4*)(part + off);
  float4 v1 = *(const float4*)(part + (size_t)1 * NROWS * CD + off);
  float4 v2 = *(const float4*)(part + (size_t)2 * NROWS * CD + off);
  float4 v3 = *(const float4*)(part + (size_t)3 * NROWS * CD + off);
  float4 b  = *(const float4*)(bdown + tx * 4);
  float4 v;
  v.x = (v0.x + v1.x) + (v2.x + v3.x) + b.x;
  v.y = (v0.y + v1.y) + (v2.y + v3.y) + b.y;
  v.z = (v0.z + v1.z) + (v2.z + v3.z) + b.z;
  v.w = (v0.w + v1.w) + (v2.w + v3.w) + b.w;

  float ss = v.x * v.x + v.y * v.y + v.z * v.z + v.w * v.w;
  #pragma unroll
  for (int m = 1; m < 16; m <<= 1) ss += __shfl_xor(ss, m, 64);
  float inv = 1.0f / sqrtf(ss);   // uniform per-row scale: argmin-safe
  float4 zv; zv.x = v.x * inv; zv.y = v.y * inv; zv.z = v.z * inv; zv.w = v.w * inv;
  *(float4*)(ws + WS_Z + off) = zv;
  if (tx == 0) (ws + WS_ZN2)[row] = ss * inv * inv;
}

// ------------- K1 legacy (used only if ws too small for split-K partials)
__global__ __launch_bounds__(256) void k1_down(const float* __restrict__ x,
                                               const float* __restrict__ W,
                                               const float* __restrict__ bdown,
                                               float* __restrict__ ws) {
  __shared__ float xs[64][68];
  __shared__ float wls[64][68];
  const int t = threadIdx.x;
  const int row0 = blockIdx.x * 64;
  const int tx = t & 15, ty = t >> 4;

  int pr[4], pseg[4];
  #pragma unroll
  for (int it = 0; it < 4; ++it) { int c = t + it * 256; pr[it] = c >> 4; pseg[it] = c & 15; }

  float4 px[4], pw[4];
  #pragma unroll
  for (int it = 0; it < 4; ++it) {
    px[it] = *(const float4*)(x + (size_t)(row0 + pr[it]) * DM + pseg[it] * 4);
    pw[it] = *(const float4*)(W + (size_t)pr[it] * DM + pseg[it] * 4);
  }

  float acc[4][4];
  #pragma unroll
  for (int i = 0; i < 4; i++)
    #pragma unroll
    for (int j = 0; j < 4; j++) acc[i][j] = 0.f;

  for (int kt = 0; kt < 16; ++kt) {
    __syncthreads();
    #pragma unroll
    for (int it = 0; it < 4; ++it) {
      *(float4*)(&xs[pr[it]][pseg[it] * 4]) = px[it];
      *(float4*)(&wls[pr[it]][pseg[it] * 4]) = pw[it];
    }
    __syncthreads();
    if (kt < 15) {
      const int k0 = (kt + 1) * 64;
      #pragma unroll
      for (int it = 0; it < 4; ++it) {
        px[it] = *(const float4*)(x + (size_t)(row0 + pr[it]) * DM + k0 + pseg[it] * 4);
        pw[it] = *(const float4*)(W + (size_t)pr[it] * DM + k0 + pseg[it] * 4);
      }
    }
    #pragma unroll 4
    for (int k = 0; k < 64; k += 4) {
      float4 xv[4], wv[4];
      #pragma unroll
      for (int i = 0; i < 4; i++) xv[i] = *(const float4*)(&xs[ty * 4 + i][k]);
      #pragma unroll
      for (int j = 0; j < 4; j++) wv[j] = *(const float4*)(&wls[tx * 4 + j][k]);
      #pragma unroll
      for (int i = 0; i < 4; i++)
        #pragma unroll
        for (int j = 0; j < 4; j++)
          acc[i][j] = fmaf(xv[i].x, wv[j].x, fmaf(xv[i].y, wv[j].y,
                      fmaf(xv[i].z, wv[j].z, fmaf(xv[i].w, wv[j].w, acc[i][j]))));
    }
  }

  #pragma unroll
  for (int j = 0; j < 4; j++) {
    float bj = bdown[tx * 4 + j];
    #pragma unroll
    for (int i = 0; i < 4; i++) acc[i][j] += bj;
  }

  float* z = ws + WS_Z;
  float* zn2 = ws + WS_ZN2;
  #pragma unroll
  for (int i = 0; i < 4; i++) {
    float ss = acc[i][0] * acc[i][0] + acc[i][1] * acc[i][1] +
               acc[i][2] * acc[i][2] + acc[i][3] * acc[i][3];
    #pragma unroll
    for (int m = 1; m < 16; m <<= 1) ss += __shfl_xor(ss, m, 64);
    float inv = 1.0f / sqrtf(ss);
    float4 zv;
    zv.x = acc[i][0] * inv; zv.y = acc[i][1] * inv;
    zv.z = acc[i][2] * inv; zv.w = acc[i][3] * inv;
    int row = row0 + ty * 4 + i;
    *(float4*)(z + (size_t)row * CD + tx * 4) = zv;
    if (tx == 0) zn2[row] = ss * inv * inv;
  }
}

// ---- K2: distance GEMM + per-row argmin (per 512-code quarter) + column-min
// EXACT R8/R10 kernel (proven 70.7us, VALUBusy 61%, occ 38.8%): z resident
// full-d, per-tile c staging + reg prefetch, 3 barriers/tile, 8 rows x 4
// codes, grid 512 = 2 blocks/CU (16 waves/CU).
__global__ __launch_bounds__(512) void k2_dist(const float* __restrict__ cbp,
                                               float* __restrict__ ws) {
  __shared__ float zT[64][132];   // [d][row 0..127]
  __shared__ float cT[64][132];   // [d][code']
  __shared__ float cn2s[128];
  __shared__ float zn2s[128];
  __shared__ unsigned colmin[128];

  const int t = threadIdx.x;
  const int gq = blockIdx.x & 3;           // code quarter: 512 codes
  const int rt = blockIdx.x >> 2;          // 0..127 rowtile
  const int row0 = rt << 7;                // 128 rows
  const int batch = rt >> 4;               // 16 rowtiles per batch
  const int tx = t & 31, ty = t >> 5;      // tx: 32 code-groups(x4), ty: 16 row-groups(x8)
  const float* z = ws + WS_Z;
  const float* cn2p = ws + WS_CN2;
  unsigned* cdist = (unsigned*)(ws + WS_CDIST) + (size_t)batch * KC;

  if (t < 128) zn2s[t] = (ws + WS_ZN2)[row0 + t];

  // stage zT once: 128 rows x 64 d; 4 threads/row, 4 segs (16 d) each
  {
    const int sr = t >> 2, sp = t & 3;
    float4 v[4];
    #pragma unroll
    for (int it = 0; it < 4; ++it)
      v[it] = *(const float4*)(z + (size_t)(row0 + sr) * CD + (sp + 4 * it) * 4);
    #pragma unroll
    for (int it = 0; it < 4; ++it) {
      const int sg4 = (sp + 4 * it) * 4;
      zT[sg4 + 0][sr] = v[it].x; zT[sg4 + 1][sr] = v[it].y;
      zT[sg4 + 2][sr] = v[it].z; zT[sg4 + 3][sr] = v[it].w;
    }
  }

  // c staging geometry: 128 codes/tile, 4 threads/code, 4 segs each
  const int cr = t >> 2, cp = t & 3;
  const int ccol = cr ^ (((cr >> 5) & 3) << 2);   // swizzled cT column
  float4 pc[4];
  auto ldc = [&](int lt) {
    const int code = gq * 512 + lt * 128 + cr;    // 0-based in [0,2048)
    #pragma unroll
    for (int it = 0; it < 4; ++it)
      pc[it] = (code < KC) ? *(const float4*)(cbp + (size_t)(code + 1) * CD + (cp + 4 * it) * 4)
                           : make_float4(0.f, 0.f, 0.f, 0.f);
  };
  ldc(0);

  float bestv[8];
  int besti[8];
  #pragma unroll
  for (int i = 0; i < 8; i++) { bestv[i] = __uint_as_float(F32_INF_BITS); besti[i] = 0; }

  const int ccol0 = (tx * 4) ^ (((tx >> 3) & 3) << 2);   // read col for 4 codes

  for (int lt = 0; lt < 4; ++lt) {
    __syncthreads();   // prev tile fully drained (and zT ready on first iter)
    #pragma unroll
    for (int it = 0; it < 4; ++it) {
      const int sg4 = (cp + 4 * it) * 4;
      cT[sg4 + 0][ccol] = pc[it].x; cT[sg4 + 1][ccol] = pc[it].y;
      cT[sg4 + 2][ccol] = pc[it].z; cT[sg4 + 3][ccol] = pc[it].w;
    }
    if (t < 128) {
      cn2s[t] = cn2p[gq * 512 + lt * 128 + t];   // [2047] = +INF pad
      colmin[t] = F32_INF_BITS;
    }
    __syncthreads();
    if (lt < 3) ldc(lt + 1);       // prefetch next tile's codes into regs

    float acc[8][4];
    #pragma unroll
    for (int i = 0; i < 8; i++)
      #pragma unroll
      for (int j = 0; j < 4; j++) acc[i][j] = 0.f;

    #pragma unroll 8
    for (int d = 0; d < 64; ++d) {
      float4 za = *(const float4*)(&zT[d][ty * 8]);
      float4 zb = *(const float4*)(&zT[d][ty * 8 + 4]);
      float4 cv = *(const float4*)(&cT[d][ccol0]);
      float zz[8] = {za.x, za.y, za.z, za.w, zb.x, zb.y, zb.z, zb.w};
      float cc[4] = {cv.x, cv.y, cv.z, cv.w};
      #pragma unroll
      for (int i = 0; i < 8; i++)
        #pragma unroll
        for (int j = 0; j < 4; j++)
          acc[i][j] = fmaf(zz[i], cc[j], acc[i][j]);
    }

    // epilogue: score = cn2 - 2*dot (zn2 const per row: argmin-equivalent)
    const int jbase = gq * 512 + lt * 128;
    #pragma unroll
    for (int jl = 0; jl < 4; ++jl) {
      const int jloc = tx * 4 + jl;
      const int jg = jbase + jloc;
      const float c2 = cn2s[jloc];
      float colv = __uint_as_float(F32_INF_BITS);
      #pragma unroll
      for (int i = 0; i < 8; ++i) {
        float s = fmaf(-2.f, acc[i][jl], c2);
        if (s < bestv[i]) { bestv[i] = s; besti[i] = jg; }  // (lt,jl) ascending: first-index ties
        float v = zn2s[ty * 8 + i] + s;
        v = v < 0.f ? 0.f : v;          // clamp(d2,0): monotone under sqrt/min
        colv = v < colv ? v : colv;
      }
      // reduce colv across the 2 ty values in this wave (lane ^32 shares tx)
      colv = fminf(colv, __shfl_xor(colv, 32, 64));
      if ((t & 32) == 0) atomicMin(&colmin[jloc], __float_as_uint(colv));
    }
    __syncthreads();
    if (t < 128) {
      const int jg2 = jbase + t;
      if (jg2 < KC) atomicMin(&cdist[jg2], colmin[t]);
    }
  }

  // argmin reduce across the 32 tx lanes (masks 1..16 stay within same ty)
  #pragma unroll
  for (int m = 1; m <= 16; m <<= 1) {
    #pragma unroll
    for (int i = 0; i < 8; i++) {
      float ov = __shfl_xor(bestv[i], m, 64);
      int oi = __shfl_xor(besti[i], m, 64);
      if (ov < bestv[i] || (ov == bestv[i] && oi < besti[i])) { bestv[i] = ov; besti[i] = oi; }
    }
  }
  if (tx == 0) {
    #pragma unroll
    for (int i = 0; i < 8; i++) {
      const int row = row0 + ty * 8 + i;
      (ws + WS_BV)[(size_t)gq * NROWS + row] = bestv[i];
      ((int*)(ws + WS_BI))[(size_t)gq * NROWS + row] = besti[i] + 1;
    }
  }
}

// ------- K3: inline quarter-argmin merge + gather hard codes + commitment
//         partials + scatter sums/bincounts (k2b fused in).
__global__ __launch_bounds__(256) void k3_scatter(const float* __restrict__ cb,
                                                  float* __restrict__ ws,
                                                  float* __restrict__ out) {
  const int t = threadIdx.x;
  const int lane = t & 63;
  const int w = t >> 6;
  const int rowbase = blockIdx.x * 32 + w * 8;
  const float* z = ws + WS_Z;

  // inline merge of the 4 quarter-argmins (ascending quarters, strict < ->
  // lowest quarter wins ties = first occurrence; identical to old k2b).
  const int myrow = rowbase + (lane & 7);
  float bv = (ws + WS_BV)[myrow];
  int myidx = ((const int*)(ws + WS_BI))[myrow];
  #pragma unroll
  for (int g2 = 1; g2 < 4; ++g2) {
    float v = (ws + WS_BV)[(size_t)g2 * NROWS + myrow];
    int i2 = ((const int*)(ws + WS_BI))[(size_t)g2 * NROWS + myrow];
    if (v < bv) { bv = v; myidx = i2; }
  }
  if (lane < 8) out[OUT_IDX + myrow] = (float)myidx;

  float sq = 0.f;
  #pragma unroll
  for (int r = 0; r < 8; ++r) {
    const int idx = __shfl(myidx, r, 8);   // idx for row rowbase+r (group-uniform)
    const int row = rowbase + r;
    const float c = cb[(size_t)idx * CD + lane];
    const float zv = z[(size_t)row * CD + lane];
    out[OUT_HARD + (size_t)row * CD + lane] = zv + (c - zv);  // matches z + sg(hard - z)
    const float d = c - zv;
    sq = fmaf(d, d, sq);
    atomicAdd(ws + WS_SUMS + (size_t)idx * CD + lane, zv);
    if (lane == 0) atomicAdd((unsigned*)(ws + WS_BINC) + idx, 1u);
  }

  __shared__ float red[4];
  #pragma unroll
  for (int m = 1; m < 64; m <<= 1) sq += __shfl_xor(sq, m, 64);
  if (lane == 0) red[w] = sq;
  __syncthreads();
  if (t == 0) (ws + WS_COMMIT)[blockIdx.x] = red[0] + red[1] + red[2] + red[3];
}

// --------- K4a: new_cs + n + losses (single block, small data only)
__global__ __launch_bounds__(1024) void k4a_stats(const float* __restrict__ cs_in,
                                                  float* __restrict__ ws,
                                                  float* __restrict__ out) {
  __shared__ float red[1024];
  const int t = threadIdx.x;
  const unsigned* binc = (const unsigned*)(ws + WS_BINC);

  float npart = 0.f;
  #pragma unroll
  for (int i = t; i < NC; i += 1024) {
    float nc = DECAY * cs_in[i] + (1.f - DECAY) * (float)binc[i];
    out[OUT_CS + i] = nc;
    npart += nc;
  }
  red[t] = npart; __syncthreads();
  for (int s = 512; s > 0; s >>= 1) { if (t < s) red[t] += red[t + s]; __syncthreads(); }
  if (t == 0) (ws + WS_N)[0] = red[0];
  __syncthreads();

  float cpart = 0.f;
  for (int j = t; j < K3_BLOCKS; j += 1024) cpart += (ws + WS_COMMIT)[j];
  red[t] = cpart; __syncthreads();
  for (int s = 512; s > 0; s >>= 1) { if (t < s) red[t] += red[t + s]; __syncthreads(); }
  float commit = red[0]; __syncthreads();

  const unsigned* cdist = (const unsigned*)(ws + WS_CDIST);
  float lsum = 0.f, ccount = 0.f;
  for (int j = t; j < KC; j += 1024) {
    if (binc[j + 1] == 0u) {
      ccount += 1.f;
      float srow = 0.f;
      #pragma unroll
      for (int b = 0; b < NB; b++) srow += sqrtf(__uint_as_float(cdist[b * KC + j]));
      lsum += srow;
    }
  }
  red[t] = lsum; __syncthreads();
  for (int s = 512; s > 0; s >>= 1) { if (t < s) red[t] += red[t + s]; __syncthreads(); }
  float totloss = red[0]; __syncthreads();
  red[t] = ccount; __syncthreads();
  for (int s = 512; s > 0; s >>= 1) { if (t < s) red[t] += red[t + s]; __syncthreads(); }
  float cnt = red[0] * (float)NB;
  if (t == 0) {
    out[OUT_COMMIT] = commit / (float)(NROWS * CD);
    out[OUT_EMB] = totloss / fmaxf(cnt, 1.f);
  }
}

// --------- K4b: new_csum, centroids, new_cb (512 blocks x 256)
__global__ __launch_bounds__(256) void k4b_update(const float* __restrict__ cb,
                                                  const float* __restrict__ csum_in,
                                                  const float* __restrict__ ws,
                                                  float* __restrict__ out) {
  const int e = blockIdx.x * 256 + threadIdx.x;   // 0 .. NC*CD-1
  const int k = e >> 6;
  const unsigned* binc = (const unsigned*)(ws + WS_BINC);
  const float n = (ws + WS_N)[0];
  const float denom = n + (float)NC * 1e-5f;

  float ncsum = DECAY * csum_in[e] + (1.f - DECAY) * (ws + WS_SUMS)[e];
  out[OUT_CSUM + e] = ncsum;
  float smoothed = (out[OUT_CS + k] + 1e-5f) * n / denom;
  float cent = ncsum / smoothed;
  float v = (binc[k] != 0u) ? cent : cb[e];
  if (k == 0) v = 0.f;
  out[OUT_CB + e] = v;
}

extern "C" void kernel_launch(void* const* d_in, const int* in_sizes, int n_in,
                              void* d_out, int out_size, void* d_ws, size_t ws_size,
                              hipStream_t stream) {
  const float* x    = (const float*)d_in[0];
  const float* W    = (const float*)d_in[1];
  const float* b    = (const float*)d_in[2];
  const float* cb   = (const float*)d_in[3];
  const float* cs   = (const float*)d_in[4];
  const float* csum = (const float*)d_in[5];
  float* out = (float*)d_out;
  float* ws  = (float*)d_ws;

  // split-K path needs partials: (WS_PART + 4*NROWS*CD) floats
  const size_t need = ((size_t)WS_PART + (size_t)4 * NROWS * CD) * sizeof(float);
  const bool use_split = ws_size >= need;   // host-side, deterministic

  hipLaunchKernelGGL(k0_init, dim3(512), dim3(256), 0, stream, cb, ws);
  if (use_split) {
    hipLaunchKernelGGL(k1_split,  dim3(512),  dim3(256), 0, stream, x, W, ws);
    hipLaunchKernelGGL(k1_reduce, dim3(1024), dim3(256), 0, stream, b, ws);
  } else {
    hipLaunchKernelGGL(k1_down, dim3(256), dim3(256), 0, stream, x, W, b, ws);
  }
  hipLaunchKernelGGL(k2_dist,   dim3(512),       dim3(512),  0, stream, cb, ws);
  hipLaunchKernelGGL(k3_scatter,dim3(K3_BLOCKS), dim3(256),  0, stream, cb, ws, out);
  hipLaunchKernelGGL(k4a_stats, dim3(1),         dim3(1024), 0, stream, cs, ws, out);
  hipLaunchKernelGGL(k4b_update,dim3(512),       dim3(256),  0, stream, cb, csum, ws, out);
}